// Round 5
// baseline (652.406 us; speedup 1.0000x reference)
//
#include <hip/hip_runtime.h>
#include <hip/hip_bf16.h>
#include <stdint.h>

#define DEV static __device__ __forceinline__

typedef __attribute__((ext_vector_type(8))) short short8;
typedef __attribute__((ext_vector_type(4))) float f32x4;
typedef __attribute__((address_space(3))) void lds_void;
typedef __attribute__((address_space(1))) void glb_void;

constexpr int CB = 2, CL = 2048, CH = 2048, CDI = 4096, CN = 16, CDTR = 128;
constexpr int BLR = CB * CL;   // 4096 total rows (b,l)
constexpr int NC = 32, LC = 64;  // scan chunks x chunk length (NC*LC == CL)

DEV ushort f2b(float f) {
  union { float f; uint32_t u; } v; v.f = f;
  uint32_t u = v.u;
  return (ushort)((u + 0x7fffu + ((u >> 16) & 1u)) >> 16);
}
DEV float b2f(ushort b) {
  union { uint32_t u; float f; } v; v.u = ((uint32_t)b) << 16;
  return v.f;
}
DEV void gload16(const ushort* g, ushort* l) {
  __builtin_amdgcn_global_load_lds((const glb_void*)g, (lds_void*)l, 16, 0, 0);
}

// ---------------- casts ----------------
__global__ void cast_kernel(const float* __restrict__ in, ushort* __restrict__ out, int n4) {
  int i = blockIdx.x * blockDim.x + threadIdx.x;
  if (i >= n4) return;
  float4 v = *(const float4*)(in + (size_t)i * 4);
  *(ushort4*)(out + (size_t)i * 4) = make_ushort4(f2b(v.x), f2b(v.y), f2b(v.z), f2b(v.w));
}

// x_proj_w [160,4096] -> bf16 [256,4096] zero-padded rows 160..255
__global__ void cast_pad_xproj_kernel(const float* __restrict__ in, ushort* __restrict__ out) {
  int i = blockIdx.x * blockDim.x + threadIdx.x;
  if (i >= (256 * 4096 / 4)) return;
  int idx = i * 4;
  int r = idx >> 12;
  ushort4 o;
  if (r < 160) {
    float4 v = *(const float4*)(in + idx);
    o = make_ushort4(f2b(v.x), f2b(v.y), f2b(v.z), f2b(v.w));
  } else {
    o = make_ushort4(0, 0, 0, 0);
  }
  *(ushort4*)(out + idx) = o;
}

// xdbl fp32 [4096,256] cols 0..127 -> dlt bf16 [4096,128]
__global__ void dlt_cast_kernel(const float* __restrict__ xdbl, ushort* __restrict__ dlt) {
  int i = blockIdx.x * blockDim.x + threadIdx.x;
  if (i >= (BLR * CDTR / 4)) return;
  int idx = i * 4;
  int m = idx >> 7, c = idx & 127;
  float4 v = *(const float4*)(xdbl + (size_t)m * 256 + c);
  *(ushort4*)(dlt + idx) = make_ushort4(f2b(v.x), f2b(v.y), f2b(v.z), f2b(v.w));
}

// ---------------- depthwise causal conv1d + silu ----------------
__global__ void conv_silu_kernel(const ushort* __restrict__ xr, const float* __restrict__ w,
                                 const float* __restrict__ bias, ushort* __restrict__ u) {
  int t = blockIdx.x * blockDim.x + threadIdx.x;
  if (t >= BLR * CDI / 2) return;
  int d2 = t & (CDI / 2 - 1);
  int bl = t >> 11;
  int l = bl & (CL - 1);
  int d = d2 << 1;
  float4 w0 = *(const float4*)(w + (size_t)d * 4);
  float4 w1 = *(const float4*)(w + (size_t)d * 4 + 4);
  float wa0[4] = {w0.x, w0.y, w0.z, w0.w};
  float wa1[4] = {w1.x, w1.y, w1.z, w1.w};
  float a0 = bias[d], a1 = bias[d + 1];
#pragma unroll
  for (int k = 0; k < 4; ++k) {
    int ls = l - 3 + k;
    if (ls >= 0) {
      ushort2 xv = *(const ushort2*)(xr + (size_t)(bl - 3 + k) * 8192 + d);
      a0 = fmaf(wa0[k], b2f(xv.x), a0);
      a1 = fmaf(wa1[k], b2f(xv.y), a1);
    }
  }
  float s0 = a0 / (1.f + __expf(-a0));
  float s1 = a1 / (1.f + __expf(-a1));
  *(ushort2*)(u + (size_t)bl * 4096 + d) = make_ushort2(f2b(s0), f2b(s1));
}

// ---------------- 128x128 bf16 MFMA GEMM (proven; GEMM2/GEMM3) ----------------
template<int EPI>
__global__ __launch_bounds__(256, 2)
void gemm_bt_kernel(const ushort* __restrict__ A, const ushort* __restrict__ Bw,
                    void* __restrict__ Cp, const float* __restrict__ bias,
                    int M, int N, int K) {
  __shared__ ushort sA[128 * 32];
  __shared__ ushort sB[128 * 32];
  const int tid = threadIdx.x;
  const int bm = blockIdx.x, bn = blockIdx.y;
  const int w = tid >> 6, l = tid & 63;
  const int wr = w >> 1, wc = w & 1;
  const int q = l >> 4, r = l & 15;

  f32x4 acc[4][4] = {};

  const ushort* Ab = A + (size_t)bm * 128 * K;
  const ushort* Bb = Bw + (size_t)bn * 128 * K;
  const int nk = K >> 5;
  for (int kt = 0; kt < nk; ++kt) {
    const int k0 = kt << 5;
#pragma unroll
    for (int i = 0; i < 2; ++i) {
      const int chunk = i * 256 + tid;
      const int row = chunk >> 2;
      const int cofs = (chunk & 3) << 3;
      gload16(Ab + (size_t)row * K + k0 + cofs, sA + chunk * 8);
      gload16(Bb + (size_t)row * K + k0 + cofs, sB + chunk * 8);
    }
    __syncthreads();
    short8 af[4], bfg[4];
#pragma unroll
    for (int i = 0; i < 4; ++i) {
      af[i]  = *(const short8*)(sA + (wr * 64 + i * 16 + r) * 32 + q * 8);
      bfg[i] = *(const short8*)(sB + (wc * 64 + i * 16 + r) * 32 + q * 8);
    }
#pragma unroll
    for (int i = 0; i < 4; ++i)
#pragma unroll
      for (int j = 0; j < 4; ++j)
        acc[i][j] = __builtin_amdgcn_mfma_f32_16x16x32_bf16(af[i], bfg[j], acc[i][j], 0, 0, 0);
    __syncthreads();
  }

  const int m0 = bm * 128 + wr * 64;
  const int n0 = bn * 128 + wc * 64;
#pragma unroll
  for (int i = 0; i < 4; ++i) {
#pragma unroll
    for (int j = 0; j < 4; ++j) {
#pragma unroll
      for (int v = 0; v < 4; ++v) {
        const int grow = m0 + i * 16 + q * 4 + v;
        const int gcol = n0 + j * 16 + r;
        const float val = acc[i][j][v];
        if (EPI == 0) {
          ((ushort*)Cp)[(size_t)grow * N + gcol] = f2b(val);
        } else if (EPI == 1) {
          ((float*)Cp)[(size_t)grow * N + gcol] = val;
        } else {
          float xv = val + bias[gcol];
          float sp = xv > 20.f ? xv : log1pf(__expf(xv));
          ((ushort*)Cp)[(size_t)grow * N + gcol] = f2b(sp);
        }
      }
    }
  }
}

// ---------------- 256-tile pipelined GEMM (GEMM1/GEMM4) ----------------
// BM=256, BN=64*NREP, BK=32. 512 threads = 8 waves (2M x 4N), wave out = 128 x 16*NREP.
// 4-slot LDS ring, stage 3 K-tiles ahead via global_load_lds, counted vmcnt
// (never 0 in loop), raw s_barrier. LDS read swizzle: 16B slot' = q ^ ((row>>1)&3),
// inverse applied to the *global source* address (linear LDS dest; rule #21).
template<int NREP, int EPI>
__global__ __launch_bounds__(512, 1)
void gemm256_kernel(const ushort* __restrict__ A, const ushort* __restrict__ Bw,
                    void* __restrict__ Cp, int N, int K) {
  constexpr int BN = 64 * NREP;
  constexpr int SBUFB = BN * 32;             // sB slot stride (ushorts)
  __shared__ ushort sA[4 * 8192];
  __shared__ ushort sB[4 * SBUFB];
  const int tid = threadIdx.x;
  const int bm = blockIdx.x, bn = blockIdx.y;
  const int w = tid >> 6, l = tid & 63;
  const int wr = w >> 2, wc = w & 3;
  const int q = l >> 4, r = l & 15;

  const ushort* Ab = A + (size_t)bm * 256 * K;
  const ushort* Bb = Bw + (size_t)bn * BN * K;
  const int c0 = tid, c1 = tid + 512;
  const int ar0 = c0 >> 2, as0 = (c0 & 3) ^ ((ar0 >> 1) & 3);
  const int ar1 = c1 >> 2, as1 = (c1 & 3) ^ ((ar1 >> 1) & 3);
  const ushort* gA0 = Ab + (size_t)ar0 * K + as0 * 8;
  const ushort* gA1 = Ab + (size_t)ar1 * K + as1 * 8;
  const ushort* gB0 = Bb + (size_t)ar0 * K + as0 * 8;
  const ushort* gB1 = Bb + (size_t)ar1 * K + as1 * 8;  // used only if NREP==4
  const int nt = K >> 5;

  auto stage = [&](int T) {
    const int Tsrc = (T < nt) ? T : (nt - 1);   // clamped tail keeps vmcnt uniform
    const int sl = T & 3;
    const int ko = Tsrc << 5;
    gload16(gA0 + ko, sA + sl * 8192 + c0 * 8);
    gload16(gA1 + ko, sA + sl * 8192 + c1 * 8);
    gload16(gB0 + ko, sB + sl * SBUFB + c0 * 8);
    if constexpr (NREP == 4) gload16(gB1 + ko, sB + sl * SBUFB + c1 * 8);
  };

  const int soff = (q ^ ((r >> 1) & 3)) * 8;
  const int aoff = (wr * 128 + r) * 32 + soff;          // + m*512
  const int boff = (wc * 16 * NREP + r) * 32 + soff;    // + n*512

  f32x4 acc[8][NREP] = {};

  stage(0); stage(1); stage(2);
  for (int t = 0; t < nt; ++t) {
    stage(t + 3);
    // wait: tile t landed (3 newer tiles = 3*LPT loads may stay in flight)
    if constexpr (NREP == 4) asm volatile("s_waitcnt vmcnt(12)" ::: "memory");
    else                     asm volatile("s_waitcnt vmcnt(9)" ::: "memory");
    __builtin_amdgcn_s_barrier();          // all waves' tile-t loads landed
    __builtin_amdgcn_sched_barrier(0);
    const ushort* At = sA + (t & 3) * 8192 + aoff;
    const ushort* Bt = sB + (t & 3) * SBUFB + boff;
    short8 bfr[NREP];
#pragma unroll
    for (int n = 0; n < NREP; ++n) bfr[n] = *(const short8*)(Bt + n * 512);
    __builtin_amdgcn_s_setprio(1);
#pragma unroll
    for (int m = 0; m < 8; ++m) {
      short8 af = *(const short8*)(At + m * 512);
#pragma unroll
      for (int n = 0; n < NREP; ++n)
        acc[m][n] = __builtin_amdgcn_mfma_f32_16x16x32_bf16(af, bfr[n], acc[m][n], 0, 0, 0);
    }
    __builtin_amdgcn_s_setprio(0);
    __builtin_amdgcn_sched_barrier(0);
    asm volatile("" ::: "memory");
    __builtin_amdgcn_s_barrier();          // all waves done reading slot t&3
  }

  const int m0g = bm * 256 + wr * 128;
  const int n0g = bn * BN + wc * 16 * NREP;
#pragma unroll
  for (int m = 0; m < 8; ++m)
#pragma unroll
    for (int n = 0; n < NREP; ++n)
#pragma unroll
      for (int v = 0; v < 4; ++v) {
        const int grow = m0g + m * 16 + q * 4 + v;
        const int gcol = n0g + n * 16 + r;
        if (EPI == 0) ((ushort*)Cp)[(size_t)grow * N + gcol] = f2b(acc[m][n][v]);
        else          ((float*)Cp)[(size_t)grow * N + gcol]  = acc[m][n][v];
      }
}

// ---------------- chunk-parallel selective scan ----------------
__global__ __launch_bounds__(256)
void scan_pass1_kernel(const ushort* __restrict__ delta_bf, const ushort* __restrict__ u_bf,
                       const float* __restrict__ xdbl, const float* __restrict__ A_log,
                       float* __restrict__ Hc, float* __restrict__ Ssum) {
  __shared__ float4 sB[LC * 4];
  const int blk = blockIdx.x;
  const int dblk = blk & 15, bc = blk >> 4;
  const int b = bc & (CB - 1), c = bc >> 1;
  const int tid = threadIdx.x;
  const int d = dblk * 256 + tid;
  const size_t rowbase = (size_t)b * CL + c * LC;

  {
    const int rr = tid >> 2, seg = tid & 3;
    sB[tid] = *(const float4*)(xdbl + (rowbase + rr) * 256 + 128 + seg * 4);
  }
  __syncthreads();

  float Ae[16];
#pragma unroll
  for (int n = 0; n < 16; ++n) Ae[n] = -__expf(A_log[(size_t)d * CN + n]);
  float h[16] = {};
  float S = 0.f;
  for (int t = 0; t < LC; ++t) {
    const float dl = b2f(delta_bf[(rowbase + t) * 4096 + d]);
    const float uu = b2f(u_bf[(rowbase + t) * 4096 + d]);
    const float du = dl * uu;
    S += dl;
#pragma unroll
    for (int q = 0; q < 4; ++q) {
      float4 bq = sB[t * 4 + q];
      h[q * 4 + 0] = __expf(Ae[q * 4 + 0] * dl) * h[q * 4 + 0] + du * bq.x;
      h[q * 4 + 1] = __expf(Ae[q * 4 + 1] * dl) * h[q * 4 + 1] + du * bq.y;
      h[q * 4 + 2] = __expf(Ae[q * 4 + 2] * dl) * h[q * 4 + 2] + du * bq.z;
      h[q * 4 + 3] = __expf(Ae[q * 4 + 3] * dl) * h[q * 4 + 3] + du * bq.w;
    }
  }
  float4* Hp = (float4*)(Hc + ((((size_t)c * CB + b) * CDI + d) << 4));
#pragma unroll
  for (int q = 0; q < 4; ++q)
    Hp[q] = make_float4(h[q * 4 + 0], h[q * 4 + 1], h[q * 4 + 2], h[q * 4 + 3]);
  Ssum[((size_t)c * CB + b) * CDI + d] = S;
}

__global__ __launch_bounds__(256)
void scan_pass2_kernel(float* __restrict__ Hc, const float* __restrict__ Ssum,
                       const float* __restrict__ A_log) {
  const int t = blockIdx.x * 256 + threadIdx.x;
  const int n = t & 15, d = (t >> 4) & (CDI - 1), b = t >> 16;
  const float Ae = -__expf(A_log[(size_t)d * CN + n]);
  float h = 0.f;
  for (int c = 1; c < NC; ++c) {
    const size_t idxp = ((size_t)(c - 1) * CB + b) * CDI + d;
    const float P = __expf(Ae * Ssum[idxp]);
    h = P * h + Hc[idxp * 16 + n];
    Hc[idxp * 16 + n] = h;
  }
}

__global__ __launch_bounds__(256)
void scan_pass3_kernel(const ushort* __restrict__ delta_bf, const ushort* __restrict__ u_bf,
                       const float* __restrict__ xdbl, const ushort* __restrict__ xr,
                       const float* __restrict__ A_log, const float* __restrict__ Dvec,
                       const float* __restrict__ Hc, ushort* __restrict__ ybf) {
  __shared__ float4 sB[LC * 4];
  __shared__ float4 sC[LC * 4];
  const int blk = blockIdx.x;
  const int dblk = blk & 15, bc = blk >> 4;
  const int b = bc & (CB - 1), c = bc >> 1;
  const int tid = threadIdx.x;
  const int d = dblk * 256 + tid;
  const size_t rowbase = (size_t)b * CL + c * LC;

  {
    const int rr = tid >> 2, seg = tid & 3;
    sB[tid] = *(const float4*)(xdbl + (rowbase + rr) * 256 + 128 + seg * 4);
    sC[tid] = *(const float4*)(xdbl + (rowbase + rr) * 256 + 144 + seg * 4);
  }
  __syncthreads();

  float Ae[16];
#pragma unroll
  for (int n = 0; n < 16; ++n) Ae[n] = -__expf(A_log[(size_t)d * CN + n]);
  float h[16];
  if (c == 0) {
#pragma unroll
    for (int n = 0; n < 16; ++n) h[n] = 0.f;
  } else {
    const float4* Hp = (const float4*)(Hc + ((((size_t)(c - 1) * CB + b) * CDI + d) << 4));
#pragma unroll
    for (int q = 0; q < 4; ++q) {
      float4 hv = Hp[q];
      h[q * 4 + 0] = hv.x; h[q * 4 + 1] = hv.y; h[q * 4 + 2] = hv.z; h[q * 4 + 3] = hv.w;
    }
  }
  const float Dd = Dvec[d];
  for (int t = 0; t < LC; ++t) {
    const float dl = b2f(delta_bf[(rowbase + t) * 4096 + d]);
    const float uu = b2f(u_bf[(rowbase + t) * 4096 + d]);
    const float du = dl * uu;
    float y = 0.f;
#pragma unroll
    for (int q = 0; q < 4; ++q) {
      float4 bq = sB[t * 4 + q];
      float4 cq = sC[t * 4 + q];
      h[q * 4 + 0] = __expf(Ae[q * 4 + 0] * dl) * h[q * 4 + 0] + du * bq.x;
      h[q * 4 + 1] = __expf(Ae[q * 4 + 1] * dl) * h[q * 4 + 1] + du * bq.y;
      h[q * 4 + 2] = __expf(Ae[q * 4 + 2] * dl) * h[q * 4 + 2] + du * bq.z;
      h[q * 4 + 3] = __expf(Ae[q * 4 + 3] * dl) * h[q * 4 + 3] + du * bq.w;
      y = fmaf(h[q * 4 + 0], cq.x, y);
      y = fmaf(h[q * 4 + 1], cq.y, y);
      y = fmaf(h[q * 4 + 2], cq.z, y);
      y = fmaf(h[q * 4 + 3], cq.w, y);
    }
    const float res = b2f(xr[(rowbase + t) * 8192 + 4096 + d]);
    const float sres = res / (1.f + __expf(-res));
    ybf[(rowbase + t) * 4096 + d] = f2b((y + uu * Dd) * sres);
  }
}

// ---------------- host ----------------
extern "C" void kernel_launch(void* const* d_in, const int* in_sizes, int n_in,
                              void* d_out, int out_size, void* d_ws, size_t ws_size,
                              hipStream_t stream) {
  (void)in_sizes; (void)n_in; (void)out_size; (void)ws_size;
  const float* x       = (const float*)d_in[0];
  const float* in_w    = (const float*)d_in[1];
  const float* conv_w  = (const float*)d_in[2];
  const float* conv_b  = (const float*)d_in[3];
  const float* xproj_w = (const float*)d_in[4];
  const float* dt_w    = (const float*)d_in[5];
  const float* dt_b    = (const float*)d_in[6];
  const float* A_log   = (const float*)d_in[7];
  const float* Dvec    = (const float*)d_in[8];
  const float* out_w   = (const float*)d_in[9];
  float* out = (float*)d_out;
  char* ws = (char*)d_ws;
  const size_t MB = 1u << 20;

  ushort* xb    = (ushort*)(ws);             // 16 MiB
  float*  Hc    = (float*)(ws);              // 16 MiB  [NC,B,DI,16]
  ushort* wout  = (ushort*)(ws);             // 16 MiB
  ushort* wb1   = (ushort*)(ws + 16 * MB);   // 32 MiB  -> u_bf after GEMM1
  ushort* u_bf  = (ushort*)(ws + 16 * MB);   // 32 MiB
  ushort* xr    = (ushort*)(ws + 48 * MB);   // 64 MiB  [4096,8192] bf16
  ushort* delta = (ushort*)(ws + 112 * MB);  // 32 MiB
  ushort* ybf   = (ushort*)(ws + 144 * MB);  // 32 MiB
  float*  xdbl  = (float*)(ws + 176 * MB);   // 4 MiB   [4096,256] padded
  ushort* dlt   = (ushort*)(ws + 180 * MB);  // 1 MiB
  ushort* wxp   = (ushort*)(ws + 181 * MB);  // 2 MiB
  ushort* wdt   = (ushort*)(ws + 183 * MB);  // 1 MiB
  float*  Ssum  = (float*)(ws + 184 * MB);   // 1 MiB   [NC,B,DI]

  auto cast = [&](const float* in, ushort* o, int n) {
    cast_kernel<<<(n / 4 + 255) / 256, 256, 0, stream>>>(in, o, n / 4);
  };

  cast(x, xb, BLR * CH);
  cast(in_w, wb1, 2 * CDI * CH);
  // GEMM1: x_and_res = x @ in_proj_w^T  [4096, 8192] bf16 (256x256 pipelined)
  gemm256_kernel<4, 0><<<dim3(BLR / 256, (2 * CDI) / 256), 512, 0, stream>>>(
      xb, wb1, xr, 2 * CDI, CH);
  // conv + silu -> u
  conv_silu_kernel<<<(BLR * CDI / 2) / 256, 256, 0, stream>>>(xr, conv_w, conv_b, u_bf);
  // GEMM2: x_dbl = u @ x_proj_w^T (N padded 160->256) [4096,256] fp32
  cast_pad_xproj_kernel<<<(256 * 4096 / 4) / 256, 256, 0, stream>>>(xproj_w, wxp);
  gemm_bt_kernel<1><<<dim3(BLR / 128, 2), 256, 0, stream>>>(
      u_bf, wxp, xdbl, nullptr, BLR, 256, CDI);
  // GEMM3: delta = softplus(dlt @ dt_proj_w^T + dt_b)  [4096,4096] bf16
  dlt_cast_kernel<<<(BLR * CDTR / 4) / 256, 256, 0, stream>>>(xdbl, dlt);
  cast(dt_w, wdt, CDI * CDTR);
  gemm_bt_kernel<2><<<dim3(BLR / 128, CDI / 128), 256, 0, stream>>>(
      dlt, wdt, delta, dt_b, BLR, CDI, CDTR);
  // chunk-parallel scan
  scan_pass1_kernel<<<NC * CB * (CDI / 256), 256, 0, stream>>>(
      delta, u_bf, xdbl, A_log, Hc, Ssum);
  scan_pass2_kernel<<<(CB * CDI * CN) / 256, 256, 0, stream>>>(Hc, Ssum, A_log);
  scan_pass3_kernel<<<NC * CB * (CDI / 256), 256, 0, stream>>>(
      delta, u_bf, xdbl, xr, A_log, Dvec, Hc, ybf);
  // GEMM4: out = y @ out_proj_w^T  [4096,2048] fp32 -> d_out (256x128 pipelined)
  cast(out_w, wout, CH * CDI);
  gemm256_kernel<2, 1><<<dim3(BLR / 256, CH / 128), 512, 0, stream>>>(
      ybf, wout, out, CH, CDI);
}

// Round 6
// 583.840 us; speedup vs baseline: 1.1174x; 1.1174x over previous
//
#include <hip/hip_runtime.h>
#include <hip/hip_bf16.h>
#include <stdint.h>

#define DEV static __device__ __forceinline__

typedef __attribute__((ext_vector_type(8))) short short8;
typedef __attribute__((ext_vector_type(4))) float f32x4;
typedef __attribute__((address_space(3))) void lds_void;
typedef __attribute__((address_space(1))) void glb_void;

constexpr int CB = 2, CL = 2048, CH = 2048, CDI = 4096, CN = 16, CDTR = 128;
constexpr int BLR = CB * CL;   // 4096 total rows (b,l)
constexpr int NC = 32, LC = 64;  // scan chunks x chunk length (NC*LC == CL)
constexpr int KSL = 8;           // GEMM2 split-K slices

DEV ushort f2b(float f) {
  union { float f; uint32_t u; } v; v.f = f;
  uint32_t u = v.u;
  return (ushort)((u + 0x7fffu + ((u >> 16) & 1u)) >> 16);
}
DEV float b2f(ushort b) {
  union { uint32_t u; float f; } v; v.u = ((uint32_t)b) << 16;
  return v.f;
}
DEV void gload16(const ushort* g, ushort* l) {
  __builtin_amdgcn_global_load_lds((const glb_void*)g, (lds_void*)l, 16, 0, 0);
}

// ---------------- casts ----------------
__global__ void cast_kernel(const float* __restrict__ in, ushort* __restrict__ out, int n4) {
  int i = blockIdx.x * blockDim.x + threadIdx.x;
  if (i >= n4) return;
  float4 v = *(const float4*)(in + (size_t)i * 4);
  *(ushort4*)(out + (size_t)i * 4) = make_ushort4(f2b(v.x), f2b(v.y), f2b(v.z), f2b(v.w));
}

// x_proj_w [160,4096] -> bf16 [256,4096] zero-padded rows 160..255
__global__ void cast_pad_xproj_kernel(const float* __restrict__ in, ushort* __restrict__ out) {
  int i = blockIdx.x * blockDim.x + threadIdx.x;
  if (i >= (256 * 4096 / 4)) return;
  int idx = i * 4;
  int r = idx >> 12;
  ushort4 o;
  if (r < 160) {
    float4 v = *(const float4*)(in + idx);
    o = make_ushort4(f2b(v.x), f2b(v.y), f2b(v.z), f2b(v.w));
  } else {
    o = make_ushort4(0, 0, 0, 0);
  }
  *(ushort4*)(out + idx) = o;
}

// ---------------- depthwise causal conv1d + silu ----------------
__global__ void conv_silu_kernel(const ushort* __restrict__ xr, const float* __restrict__ w,
                                 const float* __restrict__ bias, ushort* __restrict__ u) {
  int t = blockIdx.x * blockDim.x + threadIdx.x;
  if (t >= BLR * CDI / 2) return;
  int d2 = t & (CDI / 2 - 1);
  int bl = t >> 11;
  int l = bl & (CL - 1);
  int d = d2 << 1;
  float4 w0 = *(const float4*)(w + (size_t)d * 4);
  float4 w1 = *(const float4*)(w + (size_t)d * 4 + 4);
  float wa0[4] = {w0.x, w0.y, w0.z, w0.w};
  float wa1[4] = {w1.x, w1.y, w1.z, w1.w};
  float a0 = bias[d], a1 = bias[d + 1];
#pragma unroll
  for (int k = 0; k < 4; ++k) {
    int ls = l - 3 + k;
    if (ls >= 0) {
      ushort2 xv = *(const ushort2*)(xr + (size_t)(bl - 3 + k) * 8192 + d);
      a0 = fmaf(wa0[k], b2f(xv.x), a0);
      a1 = fmaf(wa1[k], b2f(xv.y), a1);
    }
  }
  float s0 = a0 / (1.f + __expf(-a0));
  float s1 = a1 / (1.f + __expf(-a1));
  *(ushort2*)(u + (size_t)bl * 4096 + d) = make_ushort2(f2b(s0), f2b(s1));
}

// ---------------- 128x128 bf16 MFMA GEMM (proven m97 structure) ----------------
// EPI: 0 = bf16 out, 1 = f32 out, 2 = softplus(acc+bias[n]) -> bf16
template<int EPI>
__global__ __launch_bounds__(256, 4)
void gemm_bt_kernel(const ushort* __restrict__ A, const ushort* __restrict__ Bw,
                    void* __restrict__ Cp, const float* __restrict__ bias,
                    int M, int N, int K) {
  __shared__ ushort sA[128 * 32];
  __shared__ ushort sB[128 * 32];
  const int tid = threadIdx.x;
  const int bm = blockIdx.x, bn = blockIdx.y;
  const int w = tid >> 6, l = tid & 63;
  const int wr = w >> 1, wc = w & 1;
  const int q = l >> 4, r = l & 15;

  f32x4 acc[4][4] = {};

  const ushort* Ab = A + (size_t)bm * 128 * K;
  const ushort* Bb = Bw + (size_t)bn * 128 * K;
  const int nk = K >> 5;
  for (int kt = 0; kt < nk; ++kt) {
    const int k0 = kt << 5;
#pragma unroll
    for (int i = 0; i < 2; ++i) {
      const int chunk = i * 256 + tid;
      const int row = chunk >> 2;
      const int cofs = (chunk & 3) << 3;
      gload16(Ab + (size_t)row * K + k0 + cofs, sA + chunk * 8);
      gload16(Bb + (size_t)row * K + k0 + cofs, sB + chunk * 8);
    }
    __syncthreads();
    short8 af[4], bfg[4];
#pragma unroll
    for (int i = 0; i < 4; ++i) {
      af[i]  = *(const short8*)(sA + (wr * 64 + i * 16 + r) * 32 + q * 8);
      bfg[i] = *(const short8*)(sB + (wc * 64 + i * 16 + r) * 32 + q * 8);
    }
#pragma unroll
    for (int i = 0; i < 4; ++i)
#pragma unroll
      for (int j = 0; j < 4; ++j)
        acc[i][j] = __builtin_amdgcn_mfma_f32_16x16x32_bf16(af[i], bfg[j], acc[i][j], 0, 0, 0);
    __syncthreads();
  }

  const int m0 = bm * 128 + wr * 64;
  const int n0 = bn * 128 + wc * 64;
#pragma unroll
  for (int i = 0; i < 4; ++i) {
#pragma unroll
    for (int j = 0; j < 4; ++j) {
#pragma unroll
      for (int v = 0; v < 4; ++v) {
        const int grow = m0 + i * 16 + q * 4 + v;
        const int gcol = n0 + j * 16 + r;
        const float val = acc[i][j][v];
        if (EPI == 0) {
          ((ushort*)Cp)[(size_t)grow * N + gcol] = f2b(val);
        } else if (EPI == 1) {
          ((float*)Cp)[(size_t)grow * N + gcol] = val;
        } else {
          float xv = val + bias[gcol];
          float sp = xv > 20.f ? xv : log1pf(__expf(xv));
          ((ushort*)Cp)[(size_t)grow * N + gcol] = f2b(sp);
        }
      }
    }
  }
}

// ---------------- split-K GEMM (GEMM2): partials[z][M][N] fp32 ----------------
// blockIdx.z = K-slice of length Ksl; same 128x128 tile math as gemm_bt.
__global__ __launch_bounds__(256, 4)
void gemm_btk_kernel(const ushort* __restrict__ A, const ushort* __restrict__ Bw,
                     float* __restrict__ Cpart, int N, int Ktot, int Ksl) {
  __shared__ ushort sA[128 * 32];
  __shared__ ushort sB[128 * 32];
  const int tid = threadIdx.x;
  const int bm = blockIdx.x, bn = blockIdx.y, z = blockIdx.z;
  const int w = tid >> 6, l = tid & 63;
  const int wr = w >> 1, wc = w & 1;
  const int q = l >> 4, r = l & 15;

  f32x4 acc[4][4] = {};

  const ushort* Ab = A + (size_t)bm * 128 * Ktot + z * Ksl;
  const ushort* Bb = Bw + (size_t)bn * 128 * Ktot + z * Ksl;
  const int nk = Ksl >> 5;
  for (int kt = 0; kt < nk; ++kt) {
    const int k0 = kt << 5;
#pragma unroll
    for (int i = 0; i < 2; ++i) {
      const int chunk = i * 256 + tid;
      const int row = chunk >> 2;
      const int cofs = (chunk & 3) << 3;
      gload16(Ab + (size_t)row * Ktot + k0 + cofs, sA + chunk * 8);
      gload16(Bb + (size_t)row * Ktot + k0 + cofs, sB + chunk * 8);
    }
    __syncthreads();
    short8 af[4], bfg[4];
#pragma unroll
    for (int i = 0; i < 4; ++i) {
      af[i]  = *(const short8*)(sA + (wr * 64 + i * 16 + r) * 32 + q * 8);
      bfg[i] = *(const short8*)(sB + (wc * 64 + i * 16 + r) * 32 + q * 8);
    }
#pragma unroll
    for (int i = 0; i < 4; ++i)
#pragma unroll
      for (int j = 0; j < 4; ++j)
        acc[i][j] = __builtin_amdgcn_mfma_f32_16x16x32_bf16(af[i], bfg[j], acc[i][j], 0, 0, 0);
    __syncthreads();
  }

  float* Cz = Cpart + (size_t)z * BLR * N;
  const int m0 = bm * 128 + wr * 64;
  const int n0 = bn * 128 + wc * 64;
#pragma unroll
  for (int i = 0; i < 4; ++i)
#pragma unroll
    for (int j = 0; j < 4; ++j)
#pragma unroll
      for (int v = 0; v < 4; ++v)
        Cz[(size_t)(m0 + i * 16 + q * 4 + v) * N + (n0 + j * 16 + r)] = acc[i][j][v];
}

// reduce 8 partials -> xdbl fp32 [4096,256]; also emit dlt bf16 [4096,128]
__global__ __launch_bounds__(256)
void reduce_xdbl_kernel(const float* __restrict__ part, float* __restrict__ xdbl,
                        ushort* __restrict__ dlt) {
  const int i = blockIdx.x * 256 + threadIdx.x;   // per float4; 262144 total
  const int idx = i * 4;
  const int row = idx >> 8, col = idx & 255;
  float4 s = make_float4(0.f, 0.f, 0.f, 0.f);
#pragma unroll
  for (int z = 0; z < KSL; ++z) {
    float4 v = *(const float4*)(part + (size_t)z * BLR * 256 + idx);
    s.x += v.x; s.y += v.y; s.z += v.z; s.w += v.w;
  }
  *(float4*)(xdbl + idx) = s;
  if (col < 128) {
    *(ushort4*)(dlt + (size_t)row * 128 + col) =
        make_ushort4(f2b(s.x), f2b(s.y), f2b(s.z), f2b(s.w));
  }
}

// ---------------- chunk-parallel selective scan ----------------
__global__ __launch_bounds__(256)
void scan_pass1_kernel(const ushort* __restrict__ delta_bf, const ushort* __restrict__ u_bf,
                       const float* __restrict__ xdbl, const float* __restrict__ A_log,
                       float* __restrict__ Hc, float* __restrict__ Ssum) {
  __shared__ float4 sB[LC * 4];
  const int blk = blockIdx.x;
  const int dblk = blk & 15, bc = blk >> 4;
  const int b = bc & (CB - 1), c = bc >> 1;
  const int tid = threadIdx.x;
  const int d = dblk * 256 + tid;
  const size_t rowbase = (size_t)b * CL + c * LC;

  {
    const int rr = tid >> 2, seg = tid & 3;
    sB[tid] = *(const float4*)(xdbl + (rowbase + rr) * 256 + 128 + seg * 4);
  }
  __syncthreads();

  float Ae[16];
#pragma unroll
  for (int n = 0; n < 16; ++n) Ae[n] = -__expf(A_log[(size_t)d * CN + n]);
  float h[16] = {};
  float S = 0.f;
  for (int t = 0; t < LC; ++t) {
    const float dl = b2f(delta_bf[(rowbase + t) * 4096 + d]);
    const float uu = b2f(u_bf[(rowbase + t) * 4096 + d]);
    const float du = dl * uu;
    S += dl;
#pragma unroll
    for (int q = 0; q < 4; ++q) {
      float4 bq = sB[t * 4 + q];
      h[q * 4 + 0] = __expf(Ae[q * 4 + 0] * dl) * h[q * 4 + 0] + du * bq.x;
      h[q * 4 + 1] = __expf(Ae[q * 4 + 1] * dl) * h[q * 4 + 1] + du * bq.y;
      h[q * 4 + 2] = __expf(Ae[q * 4 + 2] * dl) * h[q * 4 + 2] + du * bq.z;
      h[q * 4 + 3] = __expf(Ae[q * 4 + 3] * dl) * h[q * 4 + 3] + du * bq.w;
    }
  }
  float4* Hp = (float4*)(Hc + ((((size_t)c * CB + b) * CDI + d) << 4));
#pragma unroll
  for (int q = 0; q < 4; ++q)
    Hp[q] = make_float4(h[q * 4 + 0], h[q * 4 + 1], h[q * 4 + 2], h[q * 4 + 3]);
  Ssum[((size_t)c * CB + b) * CDI + d] = S;
}

__global__ __launch_bounds__(256)
void scan_pass2_kernel(float* __restrict__ Hc, const float* __restrict__ Ssum,
                       const float* __restrict__ A_log) {
  const int t = blockIdx.x * 256 + threadIdx.x;
  const int n = t & 15, d = (t >> 4) & (CDI - 1), b = t >> 16;
  const float Ae = -__expf(A_log[(size_t)d * CN + n]);
  float h = 0.f;
  for (int c = 1; c < NC; ++c) {
    const size_t idxp = ((size_t)(c - 1) * CB + b) * CDI + d;
    const float P = __expf(Ae * Ssum[idxp]);
    h = P * h + Hc[idxp * 16 + n];
    Hc[idxp * 16 + n] = h;
  }
}

__global__ __launch_bounds__(256)
void scan_pass3_kernel(const ushort* __restrict__ delta_bf, const ushort* __restrict__ u_bf,
                       const float* __restrict__ xdbl, const ushort* __restrict__ xr,
                       const float* __restrict__ A_log, const float* __restrict__ Dvec,
                       const float* __restrict__ Hc, ushort* __restrict__ ybf) {
  __shared__ float4 sB[LC * 4];
  __shared__ float4 sC[LC * 4];
  const int blk = blockIdx.x;
  const int dblk = blk & 15, bc = blk >> 4;
  const int b = bc & (CB - 1), c = bc >> 1;
  const int tid = threadIdx.x;
  const int d = dblk * 256 + tid;
  const size_t rowbase = (size_t)b * CL + c * LC;

  {
    const int rr = tid >> 2, seg = tid & 3;
    sB[tid] = *(const float4*)(xdbl + (rowbase + rr) * 256 + 128 + seg * 4);
    sC[tid] = *(const float4*)(xdbl + (rowbase + rr) * 256 + 144 + seg * 4);
  }
  __syncthreads();

  float Ae[16];
#pragma unroll
  for (int n = 0; n < 16; ++n) Ae[n] = -__expf(A_log[(size_t)d * CN + n]);
  float h[16];
  if (c == 0) {
#pragma unroll
    for (int n = 0; n < 16; ++n) h[n] = 0.f;
  } else {
    const float4* Hp = (const float4*)(Hc + ((((size_t)(c - 1) * CB + b) * CDI + d) << 4));
#pragma unroll
    for (int q = 0; q < 4; ++q) {
      float4 hv = Hp[q];
      h[q * 4 + 0] = hv.x; h[q * 4 + 1] = hv.y; h[q * 4 + 2] = hv.z; h[q * 4 + 3] = hv.w;
    }
  }
  const float Dd = Dvec[d];
  for (int t = 0; t < LC; ++t) {
    const float dl = b2f(delta_bf[(rowbase + t) * 4096 + d]);
    const float uu = b2f(u_bf[(rowbase + t) * 4096 + d]);
    const float du = dl * uu;
    float y = 0.f;
#pragma unroll
    for (int q = 0; q < 4; ++q) {
      float4 bq = sB[t * 4 + q];
      float4 cq = sC[t * 4 + q];
      h[q * 4 + 0] = __expf(Ae[q * 4 + 0] * dl) * h[q * 4 + 0] + du * bq.x;
      h[q * 4 + 1] = __expf(Ae[q * 4 + 1] * dl) * h[q * 4 + 1] + du * bq.y;
      h[q * 4 + 2] = __expf(Ae[q * 4 + 2] * dl) * h[q * 4 + 2] + du * bq.z;
      h[q * 4 + 3] = __expf(Ae[q * 4 + 3] * dl) * h[q * 4 + 3] + du * bq.w;
      y = fmaf(h[q * 4 + 0], cq.x, y);
      y = fmaf(h[q * 4 + 1], cq.y, y);
      y = fmaf(h[q * 4 + 2], cq.z, y);
      y = fmaf(h[q * 4 + 3], cq.w, y);
    }
    const float res = b2f(xr[(rowbase + t) * 8192 + 4096 + d]);
    const float sres = res / (1.f + __expf(-res));
    ybf[(rowbase + t) * 4096 + d] = f2b((y + uu * Dd) * sres);
  }
}

// ---------------- host ----------------
extern "C" void kernel_launch(void* const* d_in, const int* in_sizes, int n_in,
                              void* d_out, int out_size, void* d_ws, size_t ws_size,
                              hipStream_t stream) {
  (void)in_sizes; (void)n_in; (void)out_size; (void)ws_size;
  const float* x       = (const float*)d_in[0];
  const float* in_w    = (const float*)d_in[1];
  const float* conv_w  = (const float*)d_in[2];
  const float* conv_b  = (const float*)d_in[3];
  const float* xproj_w = (const float*)d_in[4];
  const float* dt_w    = (const float*)d_in[5];
  const float* dt_b    = (const float*)d_in[6];
  const float* A_log   = (const float*)d_in[7];
  const float* Dvec    = (const float*)d_in[8];
  const float* out_w   = (const float*)d_in[9];
  float* out = (float*)d_out;
  char* ws = (char*)d_ws;
  const size_t MB = 1u << 20;

  // region 0-16 MiB by lifetime: xb (GEMM1 in) -> Hc (scan) -> wout (GEMM4 w)
  // region 112-144 MiB: GEMM2 partials -> delta (GEMM3 out)
  ushort* xb    = (ushort*)(ws);             // 16 MiB
  float*  Hc    = (float*)(ws);              // 16 MiB  [NC,B,DI,16]
  ushort* wout  = (ushort*)(ws);             // 16 MiB
  ushort* wb1   = (ushort*)(ws + 16 * MB);   // 32 MiB  -> u_bf after GEMM1
  ushort* u_bf  = (ushort*)(ws + 16 * MB);   // 32 MiB
  ushort* xr    = (ushort*)(ws + 48 * MB);   // 64 MiB  [4096,8192] bf16
  float*  part  = (float*)(ws + 112 * MB);   // 32 MiB  [8,4096,256] fp32
  ushort* delta = (ushort*)(ws + 112 * MB);  // 32 MiB
  ushort* ybf   = (ushort*)(ws + 144 * MB);  // 32 MiB
  float*  xdbl  = (float*)(ws + 176 * MB);   // 4 MiB   [4096,256] padded
  ushort* dlt   = (ushort*)(ws + 180 * MB);  // 1 MiB
  ushort* wxp   = (ushort*)(ws + 181 * MB);  // 2 MiB
  ushort* wdt   = (ushort*)(ws + 183 * MB);  // 1 MiB
  float*  Ssum  = (float*)(ws + 184 * MB);   // 1 MiB   [NC,B,DI]

  auto cast = [&](const float* in, ushort* o, int n) {
    cast_kernel<<<(n / 4 + 255) / 256, 256, 0, stream>>>(in, o, n / 4);
  };

  cast(x, xb, BLR * CH);
  cast(in_w, wb1, 2 * CDI * CH);
  // GEMM1: x_and_res = x @ in_proj_w^T  [4096, 8192] bf16
  gemm_bt_kernel<0><<<dim3(BLR / 128, (2 * CDI) / 128), 256, 0, stream>>>(
      xb, wb1, xr, nullptr, BLR, 2 * CDI, CH);
  // conv + silu -> u
  conv_silu_kernel<<<(BLR * CDI / 2) / 256, 256, 0, stream>>>(xr, conv_w, conv_b, u_bf);
  // GEMM2 (split-K): x_dbl = u @ x_proj_w^T, N padded 160->256
  cast_pad_xproj_kernel<<<(256 * 4096 / 4) / 256, 256, 0, stream>>>(xproj_w, wxp);
  gemm_btk_kernel<<<dim3(BLR / 128, 2, KSL), 256, 0, stream>>>(
      u_bf, wxp, part, 256, CDI, CDI / KSL);
  reduce_xdbl_kernel<<<(BLR * 256 / 4) / 256, 256, 0, stream>>>(part, xdbl, dlt);
  // GEMM3: delta = softplus(dlt @ dt_proj_w^T + dt_b)  [4096,4096] bf16
  cast(dt_w, wdt, CDI * CDTR);
  gemm_bt_kernel<2><<<dim3(BLR / 128, CDI / 128), 256, 0, stream>>>(
      dlt, wdt, delta, dt_b, BLR, CDI, CDTR);
  // chunk-parallel scan
  scan_pass1_kernel<<<NC * CB * (CDI / 256), 256, 0, stream>>>(
      delta, u_bf, xdbl, A_log, Hc, Ssum);
  scan_pass2_kernel<<<(CB * CDI * CN) / 256, 256, 0, stream>>>(Hc, Ssum, A_log);
  scan_pass3_kernel<<<NC * CB * (CDI / 256), 256, 0, stream>>>(
      delta, u_bf, xdbl, xr, A_log, Dvec, Hc, ybf);
  // GEMM4: out = y @ out_proj_w^T  [4096,2048] fp32 -> d_out
  cast(out_w, wout, CH * CDI);
  gemm_bt_kernel<1><<<dim3(BLR / 128, CH / 128), 256, 0, stream>>>(
      ybf, wout, out, nullptr, BLR, CH, CDI);
}

// Round 7
// 547.210 us; speedup vs baseline: 1.1922x; 1.0669x over previous
//
#include <hip/hip_runtime.h>
#include <hip/hip_bf16.h>
#include <stdint.h>

#define DEV static __device__ __forceinline__

typedef __attribute__((ext_vector_type(8))) short short8;
typedef __attribute__((ext_vector_type(4))) float f32x4;
typedef __attribute__((address_space(3))) void lds_void;
typedef __attribute__((address_space(1))) void glb_void;

constexpr int CB = 2, CL = 2048, CH = 2048, CDI = 4096, CN = 16, CDTR = 128;
constexpr int BLR = CB * CL;   // 4096 total rows (b,l)
constexpr int NC = 32, LC = 64;  // scan chunks x chunk length
constexpr int KSL = 8;           // GEMM2 split-K slices

DEV ushort f2b(float f) {
  union { float f; uint32_t u; } v; v.f = f;
  uint32_t u = v.u;
  return (ushort)((u + 0x7fffu + ((u >> 16) & 1u)) >> 16);
}
DEV float b2f(ushort b) {
  union { uint32_t u; float f; } v; v.u = ((uint32_t)b) << 16;
  return v.f;
}
DEV void gload16(const ushort* g, ushort* l) {
  __builtin_amdgcn_global_load_lds((const glb_void*)g, (lds_void*)l, 16, 0, 0);
}
DEV f32x4 mfma16(short8 a, short8 b, f32x4 c) {
  return __builtin_amdgcn_mfma_f32_16x16x32_bf16(a, b, c, 0, 0, 0);
}

// ---------------- casts ----------------
__global__ void cast_kernel(const float* __restrict__ in, ushort* __restrict__ out, int n4) {
  int i = blockIdx.x * blockDim.x + threadIdx.x;
  if (i >= n4) return;
  float4 v = *(const float4*)(in + (size_t)i * 4);
  *(ushort4*)(out + (size_t)i * 4) = make_ushort4(f2b(v.x), f2b(v.y), f2b(v.z), f2b(v.w));
}

__global__ void cast_pad_xproj_kernel(const float* __restrict__ in, ushort* __restrict__ out) {
  int i = blockIdx.x * blockDim.x + threadIdx.x;
  if (i >= (256 * 4096 / 4)) return;
  int idx = i * 4;
  int r = idx >> 12;
  ushort4 o;
  if (r < 160) {
    float4 v = *(const float4*)(in + idx);
    o = make_ushort4(f2b(v.x), f2b(v.y), f2b(v.z), f2b(v.w));
  } else {
    o = make_ushort4(0, 0, 0, 0);
  }
  *(ushort4*)(out + idx) = o;
}

// ---------------- depthwise causal conv1d + silu ----------------
__global__ void conv_silu_kernel(const ushort* __restrict__ xr, const float* __restrict__ w,
                                 const float* __restrict__ bias, ushort* __restrict__ u) {
  int t = blockIdx.x * blockDim.x + threadIdx.x;
  if (t >= BLR * CDI / 2) return;
  int d2 = t & (CDI / 2 - 1);
  int bl = t >> 11;
  int l = bl & (CL - 1);
  int d = d2 << 1;
  float4 w0 = *(const float4*)(w + (size_t)d * 4);
  float4 w1 = *(const float4*)(w + (size_t)d * 4 + 4);
  float wa0[4] = {w0.x, w0.y, w0.z, w0.w};
  float wa1[4] = {w1.x, w1.y, w1.z, w1.w};
  float a0 = bias[d], a1 = bias[d + 1];
#pragma unroll
  for (int k = 0; k < 4; ++k) {
    int ls = l - 3 + k;
    if (ls >= 0) {
      ushort2 xv = *(const ushort2*)(xr + (size_t)(bl - 3 + k) * 8192 + d);
      a0 = fmaf(wa0[k], b2f(xv.x), a0);
      a1 = fmaf(wa1[k], b2f(xv.y), a1);
    }
  }
  float s0 = a0 / (1.f + __expf(-a0));
  float s1 = a1 / (1.f + __expf(-a1));
  *(ushort2*)(u + (size_t)bl * 4096 + d) = make_ushort2(f2b(s0), f2b(s1));
}

// ---------------- 128x128 bf16 MFMA GEMM (proven m97 structure) ----------------
template<int EPI>
__global__ __launch_bounds__(256, 4)
void gemm_bt_kernel(const ushort* __restrict__ A, const ushort* __restrict__ Bw,
                    void* __restrict__ Cp, const float* __restrict__ bias,
                    int M, int N, int K) {
  __shared__ ushort sA[128 * 32];
  __shared__ ushort sB[128 * 32];
  const int tid = threadIdx.x;
  const int bm = blockIdx.x, bn = blockIdx.y;
  const int w = tid >> 6, l = tid & 63;
  const int wr = w >> 1, wc = w & 1;
  const int q = l >> 4, r = l & 15;

  f32x4 acc[4][4] = {};

  const ushort* Ab = A + (size_t)bm * 128 * K;
  const ushort* Bb = Bw + (size_t)bn * 128 * K;
  const int nk = K >> 5;
  for (int kt = 0; kt < nk; ++kt) {
    const int k0 = kt << 5;
#pragma unroll
    for (int i = 0; i < 2; ++i) {
      const int chunk = i * 256 + tid;
      const int row = chunk >> 2;
      const int cofs = (chunk & 3) << 3;
      gload16(Ab + (size_t)row * K + k0 + cofs, sA + chunk * 8);
      gload16(Bb + (size_t)row * K + k0 + cofs, sB + chunk * 8);
    }
    __syncthreads();
    short8 af[4], bfg[4];
#pragma unroll
    for (int i = 0; i < 4; ++i) {
      af[i]  = *(const short8*)(sA + (wr * 64 + i * 16 + r) * 32 + q * 8);
      bfg[i] = *(const short8*)(sB + (wc * 64 + i * 16 + r) * 32 + q * 8);
    }
#pragma unroll
    for (int i = 0; i < 4; ++i)
#pragma unroll
      for (int j = 0; j < 4; ++j)
        acc[i][j] = mfma16(af[i], bfg[j], acc[i][j]);
    __syncthreads();
  }

  const int m0 = bm * 128 + wr * 64;
  const int n0 = bn * 128 + wc * 64;
#pragma unroll
  for (int i = 0; i < 4; ++i) {
#pragma unroll
    for (int j = 0; j < 4; ++j) {
#pragma unroll
      for (int v = 0; v < 4; ++v) {
        const int grow = m0 + i * 16 + q * 4 + v;
        const int gcol = n0 + j * 16 + r;
        const float val = acc[i][j][v];
        if (EPI == 0) {
          ((ushort*)Cp)[(size_t)grow * N + gcol] = f2b(val);
        } else if (EPI == 1) {
          ((float*)Cp)[(size_t)grow * N + gcol] = val;
        } else {
          float xv = val + bias[gcol];
          float sp = xv > 20.f ? xv : log1pf(__expf(xv));
          ((ushort*)Cp)[(size_t)grow * N + gcol] = f2b(sp);
        }
      }
    }
  }
}

// ---------------- 256x256 4-phase pipelined GEMM (GEMM1) ----------------
// BM=BN=256, BK=64, 8 waves (2M x 4N), per-wave 128x64 out.
// 2 LDS buffers; stage spread 2 units/phase; counted vmcnt(2) once per K-tile.
// LDS swizzle: 16B slot' = slot ^ (row&7); inverse on global source (rule #21).
template<int EPI>
__global__ __launch_bounds__(512, 1)
void gemm256p_kernel(const ushort* __restrict__ A, const ushort* __restrict__ Bw,
                     void* __restrict__ Cp, int N, int K) {
  __shared__ ushort sA[2][16384];
  __shared__ ushort sB[2][16384];
  const int tid = threadIdx.x;
  const int bm = blockIdx.x, bn = blockIdx.y;
  const int wid = tid >> 6, l = tid & 63;
  const int wr = wid >> 2, wc = wid & 3;
  const int q = l >> 4, r = l & 15;
  const int rx = r & 7;
  const int nt = K >> 6;

  const ushort* Ab = A + (size_t)bm * 256 * K;
  const ushort* Bb = Bw + (size_t)bn * 256 * K;

  // staging: unit j covers rows [j*64,(j+1)*64); thread -> (row, phys slot)
  const int srow = tid >> 3;
  const int sxor = (tid & 7) ^ (srow & 7);   // logical slot this thread supplies

  auto stageA = [&](int T, int j) {
    const int Ts = (T < nt) ? T : (nt - 1);
    gload16(Ab + (size_t)(j * 64 + srow) * K + Ts * 64 + sxor * 8,
            &sA[T & 1][0] + j * 4096 + tid * 8);
  };
  auto stageB = [&](int T, int j) {
    const int Ts = (T < nt) ? T : (nt - 1);
    gload16(Bb + (size_t)(j * 64 + srow) * K + Ts * 64 + sxor * 8,
            &sB[T & 1][0] + j * 4096 + tid * 8);
  };

  const int sl0 = (q ^ rx) * 8;          // ks=0 swizzled 16B slot (ushort off)
  const int sl1 = ((4 + q) ^ rx) * 8;    // ks=1

  f32x4 acc[8][4] = {};

  // prologue: steady-state issue order for tile0 fully + tile1's {A1,A3}
  stageA(0, 1); stageA(0, 3);
  stageB(0, 0); stageA(0, 0);
  stageB(0, 2); stageA(0, 2);
  stageB(0, 1); stageB(0, 3);
  stageA(1, 1); stageA(1, 3);
  asm volatile("s_waitcnt vmcnt(2)" ::: "memory");
  __builtin_amdgcn_s_barrier();

#define PHASE(M0, M1, S0, S1, LAST)                                        \
  {                                                                        \
    const int ra0 = (wr * 128 + (M0) * 16 + r) * 64;                       \
    const int ra1 = (wr * 128 + (M1) * 16 + r) * 64;                       \
    short8 a00 = *(const short8*)(At + ra0 + sl0);                         \
    short8 a01 = *(const short8*)(At + ra0 + sl1);                         \
    short8 a10 = *(const short8*)(At + ra1 + sl0);                         \
    short8 a11 = *(const short8*)(At + ra1 + sl1);                         \
    S0; S1;                                                                \
    if (LAST) asm volatile("s_waitcnt vmcnt(2)" ::: "memory");             \
    __builtin_amdgcn_s_barrier();                                          \
    asm volatile("s_waitcnt lgkmcnt(0)" ::: "memory");                     \
    __builtin_amdgcn_sched_barrier(0);                                     \
    __builtin_amdgcn_s_setprio(1);                                         \
    _Pragma("unroll")                                                      \
    for (int n = 0; n < 4; ++n) {                                          \
      acc[M0][n] = mfma16(a00, bf[n][0], acc[M0][n]);                      \
      acc[M0][n] = mfma16(a01, bf[n][1], acc[M0][n]);                      \
      acc[M1][n] = mfma16(a10, bf[n][0], acc[M1][n]);                      \
      acc[M1][n] = mfma16(a11, bf[n][1], acc[M1][n]);                      \
    }                                                                      \
    __builtin_amdgcn_s_setprio(0);                                         \
    __builtin_amdgcn_sched_barrier(0);                                     \
    __builtin_amdgcn_s_barrier();                                          \
  }

  for (int t = 0; t < nt; ++t) {
    const ushort* At = &sA[t & 1][0];
    const ushort* Bt = &sB[t & 1][0];
    short8 bf[4][2];
#pragma unroll
    for (int n = 0; n < 4; ++n) {
      const int br = (wc * 64 + n * 16 + r) * 64;
      bf[n][0] = *(const short8*)(Bt + br + sl0);
      bf[n][1] = *(const short8*)(Bt + br + sl1);
    }
    PHASE(6, 7, stageB(t + 1, 0), stageA(t + 1, 0), false)
    PHASE(4, 5, stageB(t + 1, 2), stageA(t + 1, 2), false)
    PHASE(2, 3, stageB(t + 1, 1), stageB(t + 1, 3), false)
    PHASE(0, 1, stageA(t + 2, 1), stageA(t + 2, 3), true)
  }
#undef PHASE

  const int m0g = bm * 256 + wr * 128;
  const int n0g = bn * 256 + wc * 64;
#pragma unroll
  for (int m = 0; m < 8; ++m)
#pragma unroll
    for (int n = 0; n < 4; ++n)
#pragma unroll
      for (int v = 0; v < 4; ++v) {
        const int grow = m0g + m * 16 + q * 4 + v;
        const int gcol = n0g + n * 16 + r;
        if (EPI == 0) ((ushort*)Cp)[(size_t)grow * N + gcol] = f2b(acc[m][n][v]);
        else          ((float*)Cp)[(size_t)grow * N + gcol]  = acc[m][n][v];
      }
}

// ---------------- split-K GEMM (GEMM2) ----------------
__global__ __launch_bounds__(256, 4)
void gemm_btk_kernel(const ushort* __restrict__ A, const ushort* __restrict__ Bw,
                     float* __restrict__ Cpart, int N, int Ktot, int Ksl) {
  __shared__ ushort sA[128 * 32];
  __shared__ ushort sB[128 * 32];
  const int tid = threadIdx.x;
  const int bm = blockIdx.x, bn = blockIdx.y, z = blockIdx.z;
  const int w = tid >> 6, l = tid & 63;
  const int wr = w >> 1, wc = w & 1;
  const int q = l >> 4, r = l & 15;

  f32x4 acc[4][4] = {};

  const ushort* Ab = A + (size_t)bm * 128 * Ktot + z * Ksl;
  const ushort* Bb = Bw + (size_t)bn * 128 * Ktot + z * Ksl;
  const int nk = Ksl >> 5;
  for (int kt = 0; kt < nk; ++kt) {
    const int k0 = kt << 5;
#pragma unroll
    for (int i = 0; i < 2; ++i) {
      const int chunk = i * 256 + tid;
      const int row = chunk >> 2;
      const int cofs = (chunk & 3) << 3;
      gload16(Ab + (size_t)row * Ktot + k0 + cofs, sA + chunk * 8);
      gload16(Bb + (size_t)row * Ktot + k0 + cofs, sB + chunk * 8);
    }
    __syncthreads();
    short8 af[4], bfg[4];
#pragma unroll
    for (int i = 0; i < 4; ++i) {
      af[i]  = *(const short8*)(sA + (wr * 64 + i * 16 + r) * 32 + q * 8);
      bfg[i] = *(const short8*)(sB + (wc * 64 + i * 16 + r) * 32 + q * 8);
    }
#pragma unroll
    for (int i = 0; i < 4; ++i)
#pragma unroll
      for (int j = 0; j < 4; ++j)
        acc[i][j] = mfma16(af[i], bfg[j], acc[i][j]);
    __syncthreads();
  }

  float* Cz = Cpart + (size_t)z * BLR * N;
  const int m0 = bm * 128 + wr * 64;
  const int n0 = bn * 128 + wc * 64;
#pragma unroll
  for (int i = 0; i < 4; ++i)
#pragma unroll
    for (int j = 0; j < 4; ++j)
#pragma unroll
      for (int v = 0; v < 4; ++v)
        Cz[(size_t)(m0 + i * 16 + q * 4 + v) * N + (n0 + j * 16 + r)] = acc[i][j][v];
}

__global__ __launch_bounds__(256)
void reduce_xdbl_kernel(const float* __restrict__ part, float* __restrict__ xdbl,
                        ushort* __restrict__ dlt) {
  const int i = blockIdx.x * 256 + threadIdx.x;
  const int idx = i * 4;
  const int row = idx >> 8, col = idx & 255;
  float4 s = make_float4(0.f, 0.f, 0.f, 0.f);
#pragma unroll
  for (int z = 0; z < KSL; ++z) {
    float4 v = *(const float4*)(part + (size_t)z * BLR * 256 + idx);
    s.x += v.x; s.y += v.y; s.z += v.z; s.w += v.w;
  }
  *(float4*)(xdbl + idx) = s;
  if (col < 128) {
    *(ushort4*)(dlt + (size_t)row * 128 + col) =
        make_ushort4(f2b(s.x), f2b(s.y), f2b(s.z), f2b(s.w));
  }
}

// ---------------- chunk-parallel selective scan ----------------
__global__ __launch_bounds__(256)
void scan_pass1_kernel(const ushort* __restrict__ delta_bf, const ushort* __restrict__ u_bf,
                       const float* __restrict__ xdbl, const float* __restrict__ A_log,
                       float* __restrict__ Hc, float* __restrict__ Ssum) {
  __shared__ float4 sB[LC * 4];
  const int blk = blockIdx.x;
  const int dblk = blk & 15, bc = blk >> 4;
  const int b = bc & (CB - 1), c = bc >> 1;
  const int tid = threadIdx.x;
  const int d = dblk * 256 + tid;
  const size_t rowbase = (size_t)b * CL + c * LC;

  {
    const int rr = tid >> 2, seg = tid & 3;
    sB[tid] = *(const float4*)(xdbl + (rowbase + rr) * 256 + 128 + seg * 4);
  }
  __syncthreads();

  float Ae[16];
#pragma unroll
  for (int n = 0; n < 16; ++n) Ae[n] = -__expf(A_log[(size_t)d * CN + n]);
  float h[16] = {};
  float S = 0.f;
  for (int t = 0; t < LC; ++t) {
    const float dl = b2f(delta_bf[(rowbase + t) * 4096 + d]);
    const float uu = b2f(u_bf[(rowbase + t) * 4096 + d]);
    const float du = dl * uu;
    S += dl;
#pragma unroll
    for (int q = 0; q < 4; ++q) {
      float4 bq = sB[t * 4 + q];
      h[q * 4 + 0] = __expf(Ae[q * 4 + 0] * dl) * h[q * 4 + 0] + du * bq.x;
      h[q * 4 + 1] = __expf(Ae[q * 4 + 1] * dl) * h[q * 4 + 1] + du * bq.y;
      h[q * 4 + 2] = __expf(Ae[q * 4 + 2] * dl) * h[q * 4 + 2] + du * bq.z;
      h[q * 4 + 3] = __expf(Ae[q * 4 + 3] * dl) * h[q * 4 + 3] + du * bq.w;
    }
  }
  float4* Hp = (float4*)(Hc + ((((size_t)c * CB + b) * CDI + d) << 4));
#pragma unroll
  for (int q = 0; q < 4; ++q)
    Hp[q] = make_float4(h[q * 4 + 0], h[q * 4 + 1], h[q * 4 + 2], h[q * 4 + 3]);
  Ssum[((size_t)c * CB + b) * CDI + d] = S;
}

__global__ __launch_bounds__(256)
void scan_pass2_kernel(float* __restrict__ Hc, const float* __restrict__ Ssum,
                       const float* __restrict__ A_log) {
  const int t = blockIdx.x * 256 + threadIdx.x;
  const int n = t & 15, d = (t >> 4) & (CDI - 1), b = t >> 16;
  const float Ae = -__expf(A_log[(size_t)d * CN + n]);
  float h = 0.f;
  for (int c = 1; c < NC; ++c) {
    const size_t idxp = ((size_t)(c - 1) * CB + b) * CDI + d;
    const float P = __expf(Ae * Ssum[idxp]);
    h = P * h + Hc[idxp * 16 + n];
    Hc[idxp * 16 + n] = h;
  }
}

__global__ __launch_bounds__(256)
void scan_pass3_kernel(const ushort* __restrict__ delta_bf, const ushort* __restrict__ u_bf,
                       const float* __restrict__ xdbl, const ushort* __restrict__ xr,
                       const float* __restrict__ A_log, const float* __restrict__ Dvec,
                       const float* __restrict__ Hc, ushort* __restrict__ ybf) {
  __shared__ float4 sB[LC * 4];
  __shared__ float4 sC[LC * 4];
  const int blk = blockIdx.x;
  const int dblk = blk & 15, bc = blk >> 4;
  const int b = bc & (CB - 1), c = bc >> 1;
  const int tid = threadIdx.x;
  const int d = dblk * 256 + tid;
  const size_t rowbase = (size_t)b * CL + c * LC;

  {
    const int rr = tid >> 2, seg = tid & 3;
    sB[tid] = *(const float4*)(xdbl + (rowbase + rr) * 256 + 128 + seg * 4);
    sC[tid] = *(const float4*)(xdbl + (rowbase + rr) * 256 + 144 + seg * 4);
  }
  __syncthreads();

  float Ae[16];
#pragma unroll
  for (int n = 0; n < 16; ++n) Ae[n] = -__expf(A_log[(size_t)d * CN + n]);
  float h[16];
  if (c == 0) {
#pragma unroll
    for (int n = 0; n < 16; ++n) h[n] = 0.f;
  } else {
    const float4* Hp = (const float4*)(Hc + ((((size_t)(c - 1) * CB + b) * CDI + d) << 4));
#pragma unroll
    for (int q = 0; q < 4; ++q) {
      float4 hv = Hp[q];
      h[q * 4 + 0] = hv.x; h[q * 4 + 1] = hv.y; h[q * 4 + 2] = hv.z; h[q * 4 + 3] = hv.w;
    }
  }
  const float Dd = Dvec[d];
  for (int t = 0; t < LC; ++t) {
    const float dl = b2f(delta_bf[(rowbase + t) * 4096 + d]);
    const float uu = b2f(u_bf[(rowbase + t) * 4096 + d]);
    const float du = dl * uu;
    float y = 0.f;
#pragma unroll
    for (int q = 0; q < 4; ++q) {
      float4 bq = sB[t * 4 + q];
      float4 cq = sC[t * 4 + q];
      h[q * 4 + 0] = __expf(Ae[q * 4 + 0] * dl) * h[q * 4 + 0] + du * bq.x;
      h[q * 4 + 1] = __expf(Ae[q * 4 + 1] * dl) * h[q * 4 + 1] + du * bq.y;
      h[q * 4 + 2] = __expf(Ae[q * 4 + 2] * dl) * h[q * 4 + 2] + du * bq.z;
      h[q * 4 + 3] = __expf(Ae[q * 4 + 3] * dl) * h[q * 4 + 3] + du * bq.w;
      y = fmaf(h[q * 4 + 0], cq.x, y);
      y = fmaf(h[q * 4 + 1], cq.y, y);
      y = fmaf(h[q * 4 + 2], cq.z, y);
      y = fmaf(h[q * 4 + 3], cq.w, y);
    }
    const float res = b2f(xr[(rowbase + t) * 8192 + 4096 + d]);
    const float sres = res / (1.f + __expf(-res));
    ybf[(rowbase + t) * 4096 + d] = f2b((y + uu * Dd) * sres);
  }
}

// ---------------- host ----------------
extern "C" void kernel_launch(void* const* d_in, const int* in_sizes, int n_in,
                              void* d_out, int out_size, void* d_ws, size_t ws_size,
                              hipStream_t stream) {
  (void)in_sizes; (void)n_in; (void)out_size; (void)ws_size;
  const float* x       = (const float*)d_in[0];
  const float* in_w    = (const float*)d_in[1];
  const float* conv_w  = (const float*)d_in[2];
  const float* conv_b  = (const float*)d_in[3];
  const float* xproj_w = (const float*)d_in[4];
  const float* dt_w    = (const float*)d_in[5];
  const float* dt_b    = (const float*)d_in[6];
  const float* A_log   = (const float*)d_in[7];
  const float* Dvec    = (const float*)d_in[8];
  const float* out_w   = (const float*)d_in[9];
  float* out = (float*)d_out;
  char* ws = (char*)d_ws;
  const size_t MB = 1u << 20;

  ushort* xb    = (ushort*)(ws);             // 16 MiB
  float*  Hc    = (float*)(ws);              // 16 MiB  [NC,B,DI,16]
  ushort* wout  = (ushort*)(ws);             // 16 MiB
  ushort* wb1   = (ushort*)(ws + 16 * MB);   // 32 MiB  -> u_bf after GEMM1
  ushort* u_bf  = (ushort*)(ws + 16 * MB);   // 32 MiB
  ushort* xr    = (ushort*)(ws + 48 * MB);   // 64 MiB  [4096,8192] bf16
  float*  part  = (float*)(ws + 112 * MB);   // 32 MiB  [8,4096,256] fp32
  ushort* delta = (ushort*)(ws + 112 * MB);  // 32 MiB
  ushort* ybf   = (ushort*)(ws + 144 * MB);  // 32 MiB
  float*  xdbl  = (float*)(ws + 176 * MB);   // 4 MiB
  ushort* dlt   = (ushort*)(ws + 180 * MB);  // 1 MiB
  ushort* wxp   = (ushort*)(ws + 181 * MB);  // 2 MiB
  ushort* wdt   = (ushort*)(ws + 183 * MB);  // 1 MiB
  float*  Ssum  = (float*)(ws + 184 * MB);   // 1 MiB

  auto cast = [&](const float* in, ushort* o, int n) {
    cast_kernel<<<(n / 4 + 255) / 256, 256, 0, stream>>>(in, o, n / 4);
  };

  cast(x, xb, BLR * CH);
  cast(in_w, wb1, 2 * CDI * CH);
  // GEMM1: x_and_res = x @ in_proj_w^T  [4096, 8192] bf16 (256^2 4-phase)
  gemm256p_kernel<0><<<dim3(BLR / 256, (2 * CDI) / 256), 512, 0, stream>>>(
      xb, wb1, xr, 2 * CDI, CH);
  // conv + silu -> u
  conv_silu_kernel<<<(BLR * CDI / 2) / 256, 256, 0, stream>>>(xr, conv_w, conv_b, u_bf);
  // GEMM2 (split-K): x_dbl = u @ x_proj_w^T, N padded 160->256
  cast_pad_xproj_kernel<<<(256 * 4096 / 4) / 256, 256, 0, stream>>>(xproj_w, wxp);
  gemm_btk_kernel<<<dim3(BLR / 128, 2, KSL), 256, 0, stream>>>(
      u_bf, wxp, part, 256, CDI, CDI / KSL);
  reduce_xdbl_kernel<<<(BLR * 256 / 4) / 256, 256, 0, stream>>>(part, xdbl, dlt);
  // GEMM3: delta = softplus(dlt @ dt_proj_w^T + dt_b)  [4096,4096] bf16
  cast(dt_w, wdt, CDI * CDTR);
  gemm_bt_kernel<2><<<dim3(BLR / 128, CDI / 128), 256, 0, stream>>>(
      dlt, wdt, delta, dt_b, BLR, CDI, CDTR);
  // chunk-parallel scan
  scan_pass1_kernel<<<NC * CB * (CDI / 256), 256, 0, stream>>>(
      delta, u_bf, xdbl, A_log, Hc, Ssum);
  scan_pass2_kernel<<<(CB * CDI * CN) / 256, 256, 0, stream>>>(Hc, Ssum, A_log);
  scan_pass3_kernel<<<NC * CB * (CDI / 256), 256, 0, stream>>>(
      delta, u_bf, xdbl, xr, A_log, Dvec, Hc, ybf);
  // GEMM4: out = y @ out_proj_w^T  [4096,2048] fp32 -> d_out
  cast(out_w, wout, CH * CDI);
  gemm_bt_kernel<1><<<dim3(BLR / 128, CH / 128), 256, 0, stream>>>(
      ybf, wout, out, nullptr, BLR, CH, CDI);
}